// Round 9
// baseline (519.769 us; speedup 1.0000x reference)
//
#include <hip/hip_runtime.h>
#include <hip/hip_bf16.h>
#include <math.h>

typedef __hip_bfloat16 bf16;
typedef __bf16 bf8v __attribute__((ext_vector_type(8)));
typedef float f4v __attribute__((ext_vector_type(4)));

__device__ inline float gelu_act(float v) {
    return 0.5f * v * (1.f + erff(v * 0.70710678118654752f));
}

// async global->LDS, 16B per lane; LDS base must be wave-uniform, HW adds lane*16.
__device__ inline void gld16(const void* g, void* l) {
    __builtin_amdgcn_global_load_lds(
        (__attribute__((address_space(1))) void*)g,
        (__attribute__((address_space(3))) void*)l, 16, 0, 0);
}

// ---------------- fp32 -> bf16 cast (vectorized, n % 1024 == 0) ----------------
__global__ __launch_bounds__(256)
void cast_f2b(const float* __restrict__ X, bf16* __restrict__ Y, long n)
{
    const long i = ((long)blockIdx.x * 256 + threadIdx.x) * 4;
    if (i + 3 < n) {
        const float4 v = *(const float4*)(X + i);
        Y[i + 0] = __float2bfloat16(v.x);
        Y[i + 1] = __float2bfloat16(v.y);
        Y[i + 2] = __float2bfloat16(v.z);
        Y[i + 3] = __float2bfloat16(v.w);
    }
}

// ---------------- GEMM 128x128 tile, ring-2 (r7-proven schedule) ----------------
// C[M,N] = epi( A[M,KR slice] @ W[N,KR slice]^T (+bias) (+R) ), A,W bf16.
// 256 threads = 4 waves (2M x 2N); per-wave C = 64x64 (acc 4x4 f4v).
// Round-9 changes vs r7 (r8's wide tile REJECTED by measurement: occupancy
// 39->23%, util 29->25%, dur +10%):
//  - EPI epilogue modes: 0 = staged store, 1 = staged store + gelu,
//    2 = direct fp32 atomicAdd (split-K partials; bias only when blockIdx.z==0).
//  - epilogue stages 32 rows/chunk (16,896 B) instead of 64 -> LDS alloc is the
//    ring only (32,768 B) -> 5 WG/CU (was 4). Work/CU unchanged; +25% concurrency
//    to hide barrier drains (the measured limiter: LDS port ~96 cyc/wave/tile vs
//    MFMA ~78, util rises only with co-resident WGs).
//  - split-K via blockIdx.z: loop K-slice KL at row-stride KR, slice z*KL.
// Conflict-free swizzle (r5-verified: conflicts 6.29M->0) and supertile XCD map
// (r7-verified: FETCH 239->51MB) unchanged. Requires gridDim.x == 64.
template<int EPI, bool HASRES, typename CT, int KL, int KR>
__global__ __launch_bounds__(256, 5)
void gemm128(const bf16* __restrict__ A, const bf16* __restrict__ W,
             const float* __restrict__ bias, const float* __restrict__ Rr,
             CT* __restrict__ C, int N)
{
    extern __shared__ __align__(16) unsigned short lds[];
    constexpr int NT   = KL / 32;
    constexpr int SLOT = 8192;

    // XCD supertile swizzle (gridDim.x == 64): XCD x owns bm strips {8x..8x+7}.
    // z (split-K) excluded from o: both K-halves of a tile share an XCD
    // (z*gy*gx is a multiple of 8), so their atomic RMW lines stay in one L2.
    const int o     = blockIdx.y * gridDim.x + blockIdx.x;
    const int local = o >> 3;
    const int bm  = (o & 7) * 8 + (local & 7);
    const int bn  = local >> 3;
    const long row0 = (long)bm * 128;
    const long col0 = (long)bn * 128;
    const long koff = (long)blockIdx.z * KL;

    const int tid  = threadIdx.x;
    const int lane = tid & 63;
    const int wave = tid >> 6;
    const int wm = wave >> 1;
    const int wn = wave & 1;
    const int fr = lane & 15;
    const int q4 = (lane >> 4) * 4;
    const int ksw = (((lane >> 4) ^ ((lane >> 1) & 3)) << 3);

    const int srow = tid >> 2;
    const int csrc = (tid & 3) ^ ((srow >> 1) & 3);
    const unsigned short* gA = (const unsigned short*)A + (row0 + srow) * (long)KR + koff + csrc * 8;
    const unsigned short* gB = (const unsigned short*)W + (col0 + srow) * (long)KR + koff + csrc * 8;
    const int woff = wave * 512;

    auto stage = [&](int t) {
        const long k0 = (long)t * 32;
        unsigned short* sl = lds + (t & 1) * SLOT + woff;
        gld16(gA + k0,                  sl);
        gld16(gA + 64 * (long)KR + k0,  sl + 2048);
        gld16(gB + k0,                  sl + 4096);
        gld16(gB + 64 * (long)KR + k0,  sl + 6144);
    };

    f4v acc[4][4];
#pragma unroll
    for (int i = 0; i < 4; ++i)
#pragma unroll
        for (int j = 0; j < 4; ++j) acc[i][j] = {0.f, 0.f, 0.f, 0.f};

    stage(0);
    __syncthreads();

#pragma unroll 2
    for (int t = 0; t < NT; ++t) {
        if (t + 1 < NT) stage(t + 1);

        const unsigned short* sA = lds + (t & 1) * SLOT;
        const unsigned short* sB = sA + 4096;

        bf8v afrag[4], bfrag[4];
#pragma unroll
        for (int x = 0; x < 4; ++x) {
            afrag[x] = *(const bf8v*)&sA[(wm * 64 + x * 16 + fr) * 32 + ksw];
            bfrag[x] = *(const bf8v*)&sB[(wn * 64 + x * 16 + fr) * 32 + ksw];
        }
#pragma unroll
        for (int mi = 0; mi < 4; ++mi)
#pragma unroll
            for (int ni = 0; ni < 4; ++ni)
                acc[mi][ni] = __builtin_amdgcn_mfma_f32_16x16x32_bf16(
                    afrag[mi], bfrag[ni], acc[mi][ni], 0, 0, 0);

        __syncthreads();
    }

    // ---------------- epilogue ----------------
    if constexpr (EPI == 2) {
        // split-K partial: direct fp32 atomicAdd into C (C pre-holds the residual).
        // D mapping: col = fr (via B row), row = q4 + r [m89/m91-verified].
        const bool addb = (blockIdx.z == 0);
#pragma unroll
        for (int ni = 0; ni < 4; ++ni) {
            const long n = col0 + wn * 64 + ni * 16 + fr;
            const float bvv = addb ? bias[n] : 0.f;
#pragma unroll
            for (int mi = 0; mi < 4; ++mi) {
                const long mb = row0 + wm * 64 + mi * 16 + q4;
#pragma unroll
                for (int r = 0; r < 4; ++r)
                    atomicAdd((float*)&C[(mb + r) * (long)N + n], acc[mi][ni][r] + bvv);
            }
        }
        return;
    }

    // coalesced LDS-staged epilogue, 32-row chunks (fits inside the 32KB ring).
    constexpr int STR = 132;
    float* eb = (float*)lds;
    const int lcol  = (tid & 31) * 4;
    const long nbase = col0 + lcol;
    const float4 b4 = *(const float4*)&bias[nbase];
    const float bb[4] = {b4.x, b4.y, b4.z, b4.w};

#pragma unroll
    for (int c = 0; c < 4; ++c) {                 // chunk rows [32c, 32c+32)
        if (c) __syncthreads();                   // close prior read-back
        if (wm == (c >> 1)) {                     // both wn waves write their halves
            const int m0 = (c & 1) * 2;           // mi in {m0, m0+1}
#pragma unroll
            for (int mi = 0; mi < 2; ++mi)
#pragma unroll
                for (int ni = 0; ni < 4; ++ni)
#pragma unroll
                    for (int r = 0; r < 4; ++r)
                        eb[((m0 + mi) * 16 + q4 + r - (c & 1) * 32) * STR
                           + wn * 64 + ni * 16 + fr] = acc[m0 + mi][ni][r];
        }
        __syncthreads();
#pragma unroll
        for (int i = 0; i < 4; ++i) {             // 8 rows/iter x 4 iters = 32 rows
            const int  rh = i * 8 + (tid >> 5);
            const long gr = row0 + c * 32 + rh;
            const f4v v = *(const f4v*)&eb[rh * STR + lcol];
            float ov[4];
#pragma unroll
            for (int cc = 0; cc < 4; ++cc) ov[cc] = v[cc] + bb[cc];
            if (HASRES) {
                const float4 r4 = *(const float4*)&Rr[gr * (long)N + nbase];
                const float ra[4] = {r4.x, r4.y, r4.z, r4.w};
#pragma unroll
                for (int cc = 0; cc < 4; ++cc) ov[cc] += ra[cc];
            }
            if (EPI == 1) {
#pragma unroll
                for (int cc = 0; cc < 4; ++cc) ov[cc] = gelu_act(ov[cc]);
            }
            if constexpr (sizeof(CT) == 2) {
                ushort4 s;
                bf16* sp = (bf16*)&s;
#pragma unroll
                for (int cc = 0; cc < 4; ++cc) sp[cc] = __float2bfloat16(ov[cc]);
                *(ushort4*)&C[gr * (long)N + nbase] = s;
            } else {
                *(float4*)&C[gr * (long)N + nbase] = make_float4(ov[0], ov[1], ov[2], ov[3]);
            }
        }
    }
}

// ---------------- per-position head attention (the einsum quirk) ----------------
__global__ __launch_bounds__(256)
void attn_kernel(const bf16* __restrict__ qkv, bf16* __restrict__ scr)
{
    __shared__ float sb[4][3392];   // per wave: q[16][65], k[16][65], v[16][65], a[16][17]
    const int tid = threadIdx.x;
    const int wave = tid >> 6, lane = tid & 63;
    const int m = blockIdx.x * 4 + wave;       // global position in [0, 8192)

    float* q = sb[wave];
    float* k = q + 1040;
    float* v = k + 1040;
    float* a = v + 1040;

    const bf16* rowp = qkv + (size_t)m * 3072;
    for (int i = lane; i < 1024; i += 64) {
        int hh = i >> 6, dd = i & 63;
        q[hh * 65 + dd] = __bfloat162float(rowp[i]);
        k[hh * 65 + dd] = __bfloat162float(rowp[1024 + i]);
        v[hh * 65 + dd] = __bfloat162float(rowp[2048 + i]);
    }
    __syncthreads();

    const int h1 = lane & 15, qd = lane >> 4;
    float e[4];
#pragma unroll
    for (int j = 0; j < 4; ++j) {
        const float* qr = q + h1 * 65;
        const float* kr = k + (qd * 4 + j) * 65;
        float s0 = 0.f;
        for (int d = 0; d < 64; ++d) s0 += qr[d] * kr[d];
        e[j] = s0 * 0.03125f;                  // 1/sqrt(1024)
    }
    float mx = fmaxf(fmaxf(e[0], e[1]), fmaxf(e[2], e[3]));
    mx = fmaxf(mx, __shfl_xor(mx, 16, 64));
    mx = fmaxf(mx, __shfl_xor(mx, 32, 64));
    float p[4], ps = 0.f;
#pragma unroll
    for (int j = 0; j < 4; ++j) { p[j] = expf(e[j] - mx); ps += p[j]; }
    ps += __shfl_xor(ps, 16, 64);
    ps += __shfl_xor(ps, 32, 64);
    const float inv = 1.f / ps;
#pragma unroll
    for (int j = 0; j < 4; ++j) a[h1 * 17 + qd * 4 + j] = p[j] * inv;
    __syncthreads();

    const int h = lane & 15, dg = lane >> 4;
    float arow[16];
#pragma unroll
    for (int l2 = 0; l2 < 16; ++l2) arow[l2] = a[h * 17 + l2];
    const int b = m >> 11, j = m & 2047;
    bf16* op = scr + (((size_t)b * 2048 + h * 128 + (j >> 4)) * 1024 + (j & 15) * 64);
    for (int t = 0; t < 16; ++t) {
        const int d = dg * 16 + t;
        float o = 0.f;
#pragma unroll
        for (int l2 = 0; l2 < 16; ++l2) o += arow[l2] * v[l2 * 65 + d];
        op[d] = __float2bfloat16(o);
    }
}

// -------- row LayerNorm over E=1024, fp32 in, fp32 out (+optional bf16 copy) --------
__global__ __launch_bounds__(256)
void ln_kernel(const float* __restrict__ X, const float* __restrict__ G,
               const float* __restrict__ Bt, float* __restrict__ Y32,
               bf16* __restrict__ Yb)
{
    __shared__ float rs[4], rq[4];
    const int tid = threadIdx.x;
    const long row = blockIdx.x;
    const float* xp = X + row * 1024;
    float x[4];
#pragma unroll
    for (int i = 0; i < 4; ++i) x[i] = xp[tid + 256 * i];

    float s = x[0] + x[1] + x[2] + x[3];
#pragma unroll
    for (int off = 32; off; off >>= 1) s += __shfl_down(s, off, 64);
    if ((tid & 63) == 0) rs[tid >> 6] = s;
    __syncthreads();
    const float mean = (rs[0] + rs[1] + rs[2] + rs[3]) * (1.f / 1024.f);

    float qv = 0.f;
#pragma unroll
    for (int i = 0; i < 4; ++i) { float d = x[i] - mean; qv += d * d; }
#pragma unroll
    for (int off = 32; off; off >>= 1) qv += __shfl_down(qv, off, 64);
    if ((tid & 63) == 0) rq[tid >> 6] = qv;
    __syncthreads();
    const float var = (rq[0] + rq[1] + rq[2] + rq[3]) * (1.f / 1024.f);
    const float rstd = rsqrtf(var + 1e-5f);

#pragma unroll
    for (int i = 0; i < 4; ++i) {
        const int e = tid + 256 * i;
        const float yv = (x[i] - mean) * rstd * G[e] + Bt[e];
        Y32[row * 1024 + e] = yv;
        if (Yb) Yb[row * 1024 + e] = __float2bfloat16(yv);
    }
}

extern "C" void kernel_launch(void* const* d_in, const int* in_sizes, int n_in,
                              void* d_out, int out_size, void* d_ws, size_t ws_size,
                              hipStream_t stream)
{
    (void)in_sizes; (void)n_in; (void)out_size;
    const float* x    = (const float*)d_in[0];
    const float* Wqkv = (const float*)d_in[1];
    const float* bqkv = (const float*)d_in[2];
    const float* Wo   = (const float*)d_in[3];
    const float* bo   = (const float*)d_in[4];
    const float* g1   = (const float*)d_in[5];
    const float* b1   = (const float*)d_in[6];
    const float* W1   = (const float*)d_in[7];
    const float* bf1  = (const float*)d_in[8];
    const float* W2   = (const float*)d_in[9];
    const float* bf2  = (const float*)d_in[10];
    const float* g2   = (const float*)d_in[11];
    const float* b2   = (const float*)d_in[12];
    float* out = (float*)d_out;

    if (ws_size < 125829120ULL) return;

    // ws layout (bytes):
    //   R1 @0, 67,108,864: qkv bf16(50.3M) -> t fp32(33.5M) -> u bf16(67M)
    //   Wqkvb @67108864 (6.3M) | Wob @73400320 (2.1M) | W1b @75497472 (8.4M)
    //   W2b @83886080 (8.4M)   | xb/scr @92274688 (16.8M) | hb @109051904 (16.8M)
    char* ws = (char*)d_ws;
    bf16* qkv   = (bf16*)(ws + 0);
    float* t    = (float*)(ws + 0);
    bf16* u     = (bf16*)(ws + 0);
    bf16* Wqkvb = (bf16*)(ws + 67108864);
    bf16* Wob   = (bf16*)(ws + 73400320);
    bf16* W1b   = (bf16*)(ws + 75497472);
    bf16* W2b   = (bf16*)(ws + 83886080);
    bf16* xb    = (bf16*)(ws + 92274688);
    bf16* scr   = (bf16*)(ws + 92274688);   // reuses xb (dead after gemm1)
    bf16* hb    = (bf16*)(ws + 109051904);
    float* h    = out;                       // fp32 h lives in d_out until gemm6

    // dynamic LDS: ring 32,768 B; epilogue 32-row stage 16,896 B -> 5 WG/CU
    constexpr unsigned LDS_128 = 32768;

    // 0) casts fp32 -> bf16
    cast_f2b<<<8192, 256, 0, stream>>>(x,    xb,    8388608);
    cast_f2b<<<3072, 256, 0, stream>>>(Wqkv, Wqkvb, 3145728);
    cast_f2b<<<1024, 256, 0, stream>>>(Wo,   Wob,   1048576);
    cast_f2b<<<4096, 256, 0, stream>>>(W1,   W1b,   4194304);
    cast_f2b<<<4096, 256, 0, stream>>>(W2,   W2b,   4194304);

    // 1) qkv = x @ Wqkv^T + bqkv            (bf16 out)   grid 64x24 = 1536 wg
    gemm128<0, false, bf16, 1024, 1024><<<dim3(64, 24), 256, LDS_128, stream>>>(xb, Wqkvb, bqkv, nullptr, qkv, 3072);
    // 2) per-position head attention + reshape scramble -> scr
    attn_kernel<<<2048, 256, 0, stream>>>(qkv, scr);
    // 3) t = scr @ Wo^T + bo + x            (fp32 out, fp32 residual)  grid 64x8 = 512 wg
    gemm128<0, true, float, 1024, 1024><<<dim3(64, 8), 256, LDS_128, stream>>>(scr, Wob, bo, x, t, 1024);
    // 4) h = LN1(t)  -> fp32 h (d_out) + bf16 hb
    ln_kernel<<<8192, 256, 0, stream>>>(t, g1, b1, h, hb);
    // 5) u = gelu(hb @ W1^T + bf1)          (bf16 out)   grid 64x32 = 2048 wg
    gemm128<1, false, bf16, 1024, 1024><<<dim3(64, 32), 256, LDS_128, stream>>>(hb, W1b, bf1, nullptr, u, 4096);
    // 6) out += u @ W2^T + bf2  (split-K x2, fp32 atomics; out pre-holds h from LN1)
    gemm128<2, false, float, 2048, 4096><<<dim3(64, 8, 2), 256, LDS_128, stream>>>(u, W2b, bf2, nullptr, out, 1024);
    // 7) out = LN2(s2) in-place, fp32 only
    ln_kernel<<<8192, 256, 0, stream>>>(out, g2, b2, out, nullptr);
}

// Round 11
// 493.866 us; speedup vs baseline: 1.0524x; 1.0524x over previous
//
#include <hip/hip_runtime.h>
#include <hip/hip_bf16.h>
#include <math.h>

typedef __hip_bfloat16 bf16;
typedef __bf16 bf8v __attribute__((ext_vector_type(8)));
typedef float f4v __attribute__((ext_vector_type(4)));

__device__ inline float gelu_act(float v) {
    return 0.5f * v * (1.f + erff(v * 0.70710678118654752f));
}

// async global->LDS, 16B per lane; LDS base must be wave-uniform, HW adds lane*16.
__device__ inline void gld16(const void* g, void* l) {
    __builtin_amdgcn_global_load_lds(
        (__attribute__((address_space(1))) void*)g,
        (__attribute__((address_space(3))) void*)l, 16, 0, 0);
}

// ---------------- fp32 -> bf16 cast (vectorized, n % 1024 == 0) ----------------
__global__ __launch_bounds__(256)
void cast_f2b(const float* __restrict__ X, bf16* __restrict__ Y, long n)
{
    const long i = ((long)blockIdx.x * 256 + threadIdx.x) * 4;
    if (i + 3 < n) {
        const float4 v = *(const float4*)(X + i);
        Y[i + 0] = __float2bfloat16(v.x);
        Y[i + 1] = __float2bfloat16(v.y);
        Y[i + 2] = __float2bfloat16(v.z);
        Y[i + 3] = __float2bfloat16(v.w);
    }
}

// ---------------- GEMM 128x128 tile, ring-2 (r7-proven schedule) ----------------
// C[M,N] = epi( A[M,KR slice] @ W[N,KR slice]^T (+bias) (+R) ), A,W bf16.
// 256 threads = 4 waves (2M x 2N); per-wave C = 64x64 (acc 4x4 f4v).
// [round-11: byte-identical resubmission of round-10 — container flake A/B;
//  r4->r5 identical-resubmit passed, establishing the flake precedent.]
// Round-10: EXACT r7 kernel (launch_bounds(256,4), 64-row staged epilogue) —
// r9's launch_bounds(256,5) over-constrained registers (VGPR 56->48, acc
// spilled to scratch: VALUBusy 47->11%, FETCH +19MB, dur +27%). REVERTED.
// Retained from r9 (verified correct, absmax unchanged): EPI=2 split-K path
// (direct fp32 atomicAdd partials; bias only on blockIdx.z==0).
// Conflict-free swizzle (r5: conflicts 6.29M->0), supertile XCD map (r7:
// FETCH 239->51MB), coalesced staged epilogue (r3: WRITE 161.6->65.5MB).
template<int EPI, bool HASRES, typename CT, int KL, int KR>
__global__ __launch_bounds__(256, 4)
void gemm128(const bf16* __restrict__ A, const bf16* __restrict__ W,
             const float* __restrict__ bias, const float* __restrict__ Rr,
             CT* __restrict__ C, int N)
{
    extern __shared__ __align__(16) unsigned short lds[];
    constexpr int NT   = KL / 32;
    constexpr int SLOT = 8192;

    // XCD supertile swizzle (gridDim.x == 64): XCD x owns bm strips {8x..8x+7}.
    // z (split-K) excluded from o: both K-halves of a tile share an XCD
    // (z*gy*gx is a multiple of 8), so their atomic RMW lines stay in one L2.
    const int o     = blockIdx.y * gridDim.x + blockIdx.x;
    const int local = o >> 3;
    const int bm  = (o & 7) * 8 + (local & 7);
    const int bn  = local >> 3;
    const long row0 = (long)bm * 128;
    const long col0 = (long)bn * 128;
    const long koff = (long)blockIdx.z * KL;

    const int tid  = threadIdx.x;
    const int lane = tid & 63;
    const int wave = tid >> 6;
    const int wm = wave >> 1;
    const int wn = wave & 1;
    const int fr = lane & 15;
    const int q4 = (lane >> 4) * 4;
    const int ksw = (((lane >> 4) ^ ((lane >> 1) & 3)) << 3);

    const int srow = tid >> 2;
    const int csrc = (tid & 3) ^ ((srow >> 1) & 3);
    const unsigned short* gA = (const unsigned short*)A + (row0 + srow) * (long)KR + koff + csrc * 8;
    const unsigned short* gB = (const unsigned short*)W + (col0 + srow) * (long)KR + koff + csrc * 8;
    const int woff = wave * 512;

    auto stage = [&](int t) {
        const long k0 = (long)t * 32;
        unsigned short* sl = lds + (t & 1) * SLOT + woff;
        gld16(gA + k0,                  sl);
        gld16(gA + 64 * (long)KR + k0,  sl + 2048);
        gld16(gB + k0,                  sl + 4096);
        gld16(gB + 64 * (long)KR + k0,  sl + 6144);
    };

    f4v acc[4][4];
#pragma unroll
    for (int i = 0; i < 4; ++i)
#pragma unroll
        for (int j = 0; j < 4; ++j) acc[i][j] = {0.f, 0.f, 0.f, 0.f};

    stage(0);
    __syncthreads();

#pragma unroll 2
    for (int t = 0; t < NT; ++t) {
        if (t + 1 < NT) stage(t + 1);

        const unsigned short* sA = lds + (t & 1) * SLOT;
        const unsigned short* sB = sA + 4096;

        bf8v afrag[4], bfrag[4];
#pragma unroll
        for (int x = 0; x < 4; ++x) {
            afrag[x] = *(const bf8v*)&sA[(wm * 64 + x * 16 + fr) * 32 + ksw];
            bfrag[x] = *(const bf8v*)&sB[(wn * 64 + x * 16 + fr) * 32 + ksw];
        }
#pragma unroll
        for (int mi = 0; mi < 4; ++mi)
#pragma unroll
            for (int ni = 0; ni < 4; ++ni)
                acc[mi][ni] = __builtin_amdgcn_mfma_f32_16x16x32_bf16(
                    afrag[mi], bfrag[ni], acc[mi][ni], 0, 0, 0);

        __syncthreads();
    }

    // ---------------- epilogue ----------------
    if constexpr (EPI == 2) {
        // split-K partial: direct fp32 atomicAdd into C (C pre-holds the residual).
        // D mapping: col = fr (via B row), row = q4 + r [m89/m91-verified; r9-verified].
        const bool addb = (blockIdx.z == 0);
#pragma unroll
        for (int ni = 0; ni < 4; ++ni) {
            const long n = col0 + wn * 64 + ni * 16 + fr;
            const float bvv = addb ? bias[n] : 0.f;
#pragma unroll
            for (int mi = 0; mi < 4; ++mi) {
                const long mb = row0 + wm * 64 + mi * 16 + q4;
#pragma unroll
                for (int r = 0; r < 4; ++r)
                    atomicAdd((float*)&C[(mb + r) * (long)N + n], acc[mi][ni][r] + bvv);
            }
        }
        return;
    }

    // coalesced LDS-staged epilogue (r3/r7-verified, 64-row chunks)
    constexpr int STR = 132;
    float* eb = (float*)lds;
    const int lcol  = (tid & 31) * 4;
    const long nbase = col0 + lcol;
    const float4 b4 = *(const float4*)&bias[nbase];
    const float bb[4] = {b4.x, b4.y, b4.z, b4.w};

#pragma unroll
    for (int h = 0; h < 2; ++h) {
        if (h) __syncthreads();
        if (wm == h) {
#pragma unroll
            for (int mi = 0; mi < 4; ++mi)
#pragma unroll
                for (int ni = 0; ni < 4; ++ni)
#pragma unroll
                    for (int r = 0; r < 4; ++r)
                        eb[(mi * 16 + q4 + r) * STR + wn * 64 + ni * 16 + fr] = acc[mi][ni][r];
        }
        __syncthreads();
#pragma unroll
        for (int i = 0; i < 8; ++i) {
            const int  rh = i * 8 + (tid >> 5);
            const long gr = row0 + h * 64 + rh;
            const f4v v = *(const f4v*)&eb[rh * STR + lcol];
            float ov[4];
#pragma unroll
            for (int c = 0; c < 4; ++c) ov[c] = v[c] + bb[c];
            if (HASRES) {
                const float4 r4 = *(const float4*)&Rr[gr * (long)N + nbase];
                const float ra[4] = {r4.x, r4.y, r4.z, r4.w};
#pragma unroll
                for (int c = 0; c < 4; ++c) ov[c] += ra[c];
            }
            if (EPI == 1) {
#pragma unroll
                for (int c = 0; c < 4; ++c) ov[c] = gelu_act(ov[c]);
            }
            if constexpr (sizeof(CT) == 2) {
                ushort4 s;
                bf16* sp = (bf16*)&s;
#pragma unroll
                for (int c = 0; c < 4; ++c) sp[c] = __float2bfloat16(ov[c]);
                *(ushort4*)&C[gr * (long)N + nbase] = s;
            } else {
                *(float4*)&C[gr * (long)N + nbase] = make_float4(ov[0], ov[1], ov[2], ov[3]);
            }
        }
    }
}

// ---------------- per-position head attention (the einsum quirk) ----------------
__global__ __launch_bounds__(256)
void attn_kernel(const bf16* __restrict__ qkv, bf16* __restrict__ scr)
{
    __shared__ float sb[4][3392];   // per wave: q[16][65], k[16][65], v[16][65], a[16][17]
    const int tid = threadIdx.x;
    const int wave = tid >> 6, lane = tid & 63;
    const int m = blockIdx.x * 4 + wave;       // global position in [0, 8192)

    float* q = sb[wave];
    float* k = q + 1040;
    float* v = k + 1040;
    float* a = v + 1040;

    const bf16* rowp = qkv + (size_t)m * 3072;
    for (int i = lane; i < 1024; i += 64) {
        int hh = i >> 6, dd = i & 63;
        q[hh * 65 + dd] = __bfloat162float(rowp[i]);
        k[hh * 65 + dd] = __bfloat162float(rowp[1024 + i]);
        v[hh * 65 + dd] = __bfloat162float(rowp[2048 + i]);
    }
    __syncthreads();

    const int h1 = lane & 15, qd = lane >> 4;
    float e[4];
#pragma unroll
    for (int j = 0; j < 4; ++j) {
        const float* qr = q + h1 * 65;
        const float* kr = k + (qd * 4 + j) * 65;
        float s0 = 0.f;
        for (int d = 0; d < 64; ++d) s0 += qr[d] * kr[d];
        e[j] = s0 * 0.03125f;                  // 1/sqrt(1024)
    }
    float mx = fmaxf(fmaxf(e[0], e[1]), fmaxf(e[2], e[3]));
    mx = fmaxf(mx, __shfl_xor(mx, 16, 64));
    mx = fmaxf(mx, __shfl_xor(mx, 32, 64));
    float p[4], ps = 0.f;
#pragma unroll
    for (int j = 0; j < 4; ++j) { p[j] = expf(e[j] - mx); ps += p[j]; }
    ps += __shfl_xor(ps, 16, 64);
    ps += __shfl_xor(ps, 32, 64);
    const float inv = 1.f / ps;
#pragma unroll
    for (int j = 0; j < 4; ++j) a[h1 * 17 + qd * 4 + j] = p[j] * inv;
    __syncthreads();

    const int h = lane & 15, dg = lane >> 4;
    float arow[16];
#pragma unroll
    for (int l2 = 0; l2 < 16; ++l2) arow[l2] = a[h * 17 + l2];
    const int b = m >> 11, j = m & 2047;
    bf16* op = scr + (((size_t)b * 2048 + h * 128 + (j >> 4)) * 1024 + (j & 15) * 64);
    for (int t = 0; t < 16; ++t) {
        const int d = dg * 16 + t;
        float o = 0.f;
#pragma unroll
        for (int l2 = 0; l2 < 16; ++l2) o += arow[l2] * v[l2 * 65 + d];
        op[d] = __float2bfloat16(o);
    }
}

// -------- row LayerNorm over E=1024, fp32 in, fp32 out (+optional bf16 copy) --------
__global__ __launch_bounds__(256)
void ln_kernel(const float* __restrict__ X, const float* __restrict__ G,
               const float* __restrict__ Bt, float* __restrict__ Y32,
               bf16* __restrict__ Yb)
{
    __shared__ float rs[4], rq[4];
    const int tid = threadIdx.x;
    const long row = blockIdx.x;
    const float* xp = X + row * 1024;
    float x[4];
#pragma unroll
    for (int i = 0; i < 4; ++i) x[i] = xp[tid + 256 * i];

    float s = x[0] + x[1] + x[2] + x[3];
#pragma unroll
    for (int off = 32; off; off >>= 1) s += __shfl_down(s, off, 64);
    if ((tid & 63) == 0) rs[tid >> 6] = s;
    __syncthreads();
    const float mean = (rs[0] + rs[1] + rs[2] + rs[3]) * (1.f / 1024.f);

    float qv = 0.f;
#pragma unroll
    for (int i = 0; i < 4; ++i) { float d = x[i] - mean; qv += d * d; }
#pragma unroll
    for (int off = 32; off; off >>= 1) qv += __shfl_down(qv, off, 64);
    if ((tid & 63) == 0) rq[tid >> 6] = qv;
    __syncthreads();
    const float var = (rq[0] + rq[1] + rq[2] + rq[3]) * (1.f / 1024.f);
    const float rstd = rsqrtf(var + 1e-5f);

#pragma unroll
    for (int i = 0; i < 4; ++i) {
        const int e = tid + 256 * i;
        const float yv = (x[i] - mean) * rstd * G[e] + Bt[e];
        Y32[row * 1024 + e] = yv;
        if (Yb) Yb[row * 1024 + e] = __float2bfloat16(yv);
    }
}

extern "C" void kernel_launch(void* const* d_in, const int* in_sizes, int n_in,
                              void* d_out, int out_size, void* d_ws, size_t ws_size,
                              hipStream_t stream)
{
    (void)in_sizes; (void)n_in; (void)out_size;
    const float* x    = (const float*)d_in[0];
    const float* Wqkv = (const float*)d_in[1];
    const float* bqkv = (const float*)d_in[2];
    const float* Wo   = (const float*)d_in[3];
    const float* bo   = (const float*)d_in[4];
    const float* g1   = (const float*)d_in[5];
    const float* b1   = (const float*)d_in[6];
    const float* W1   = (const float*)d_in[7];
    const float* bf1  = (const float*)d_in[8];
    const float* W2   = (const float*)d_in[9];
    const float* bf2  = (const float*)d_in[10];
    const float* g2   = (const float*)d_in[11];
    const float* b2   = (const float*)d_in[12];
    float* out = (float*)d_out;

    if (ws_size < 125829120ULL) return;

    // ws layout (bytes):
    //   R1 @0, 67,108,864: qkv bf16(50.3M) -> t fp32(33.5M) -> u bf16(67M)
    //   Wqkvb @67108864 (6.3M) | Wob @73400320 (2.1M) | W1b @75497472 (8.4M)
    //   W2b @83886080 (8.4M)   | xb/scr @92274688 (16.8M) | hb @109051904 (16.8M)
    char* ws = (char*)d_ws;
    bf16* qkv   = (bf16*)(ws + 0);
    float* t    = (float*)(ws + 0);
    bf16* u     = (bf16*)(ws + 0);
    bf16* Wqkvb = (bf16*)(ws + 67108864);
    bf16* Wob   = (bf16*)(ws + 73400320);
    bf16* W1b   = (bf16*)(ws + 75497472);
    bf16* W2b   = (bf16*)(ws + 83886080);
    bf16* xb    = (bf16*)(ws + 92274688);
    bf16* scr   = (bf16*)(ws + 92274688);   // reuses xb (dead after gemm1)
    bf16* hb    = (bf16*)(ws + 109051904);
    float* h    = out;                       // fp32 h lives in d_out until gemm6

    constexpr unsigned LDS_128 = 33792;      // ring 32K; 64-row epi stage 33,792 -> 4 WG/CU
    constexpr unsigned LDS_SPK = 32768;      // split-K kernel: ring only

    // 0) casts fp32 -> bf16
    cast_f2b<<<8192, 256, 0, stream>>>(x,    xb,    8388608);
    cast_f2b<<<3072, 256, 0, stream>>>(Wqkv, Wqkvb, 3145728);
    cast_f2b<<<1024, 256, 0, stream>>>(Wo,   Wob,   1048576);
    cast_f2b<<<4096, 256, 0, stream>>>(W1,   W1b,   4194304);
    cast_f2b<<<4096, 256, 0, stream>>>(W2,   W2b,   4194304);

    // 1) qkv = x @ Wqkv^T + bqkv            (bf16 out)   grid 64x24 = 1536 wg
    gemm128<0, false, bf16, 1024, 1024><<<dim3(64, 24), 256, LDS_128, stream>>>(xb, Wqkvb, bqkv, nullptr, qkv, 3072);
    // 2) per-position head attention + reshape scramble -> scr
    attn_kernel<<<2048, 256, 0, stream>>>(qkv, scr);
    // 3) t = scr @ Wo^T + bo + x            (fp32 out, fp32 residual)  grid 64x8 = 512 wg
    gemm128<0, true, float, 1024, 1024><<<dim3(64, 8), 256, LDS_128, stream>>>(scr, Wob, bo, x, t, 1024);
    // 4) h = LN1(t)  -> fp32 h (d_out) + bf16 hb
    ln_kernel<<<8192, 256, 0, stream>>>(t, g1, b1, h, hb);
    // 5) u = gelu(hb @ W1^T + bf1)          (bf16 out)   grid 64x32 = 2048 wg
    gemm128<1, false, bf16, 1024, 1024><<<dim3(64, 32), 256, LDS_128, stream>>>(hb, W1b, bf1, nullptr, u, 4096);
    // 6) out += u @ W2^T + bf2  (split-K x2, fp32 atomics; out pre-holds h from LN1)
    gemm128<2, false, float, 2048, 4096><<<dim3(64, 8, 2), 256, LDS_SPK, stream>>>(u, W2b, bf2, nullptr, out, 1024);
    // 7) out = LN2(s2) in-place, fp32 only
    ln_kernel<<<8192, 256, 0, stream>>>(out, g2, b2, out, nullptr);
}

// Round 12
// 454.765 us; speedup vs baseline: 1.1429x; 1.0860x over previous
//
#include <hip/hip_runtime.h>
#include <hip/hip_bf16.h>
#include <math.h>

typedef __hip_bfloat16 bf16;
typedef __bf16 bf8v __attribute__((ext_vector_type(8)));
typedef float f4v __attribute__((ext_vector_type(4)));
typedef unsigned short u16x8 __attribute__((ext_vector_type(8)));
typedef unsigned short u16x4 __attribute__((ext_vector_type(4)));

__device__ inline float gelu_act(float v) {
    return 0.5f * v * (1.f + erff(v * 0.70710678118654752f));
}
__device__ inline float b2f(unsigned short u) {
    return __uint_as_float((unsigned)u << 16);
}
__device__ inline unsigned short f2b(float f) {
    bf16 b = __float2bfloat16(f);
    return *reinterpret_cast<unsigned short*>(&b);
}

// async global->LDS, 16B per lane; LDS base must be wave-uniform, HW adds lane*16.
__device__ inline void gld16(const void* g, void* l) {
    __builtin_amdgcn_global_load_lds(
        (__attribute__((address_space(1))) void*)g,
        (__attribute__((address_space(3))) void*)l, 16, 0, 0);
}

// ------------- fused fp32 -> bf16 casts (5 tensors, one launch) -------------
// block ranges: x 8192 | Wqkv 3072 | Wo 1024 | W1 4096 | W2 4096  = 20480
__global__ __launch_bounds__(256)
void cast_all(const float* __restrict__ x, const float* __restrict__ Wqkv,
              const float* __restrict__ Wo, const float* __restrict__ W1,
              const float* __restrict__ W2, bf16* __restrict__ xb,
              bf16* __restrict__ Wqkvb, bf16* __restrict__ Wob,
              bf16* __restrict__ W1b, bf16* __restrict__ W2b)
{
    const int b = blockIdx.x;
    const float* src; bf16* dst; long off;
    if (b < 8192)       { src = x;    dst = xb;    off = b; }
    else if (b < 11264) { src = Wqkv; dst = Wqkvb; off = b - 8192; }
    else if (b < 12288) { src = Wo;   dst = Wob;   off = b - 11264; }
    else if (b < 16384) { src = W1;   dst = W1b;   off = b - 12288; }
    else                { src = W2;   dst = W2b;   off = b - 16384; }
    const long i = (off * 256 + threadIdx.x) * 4;
    const float4 v = *(const float4*)(src + i);
    u16x4 s;
    s[0] = f2b(v.x); s[1] = f2b(v.y); s[2] = f2b(v.z); s[3] = f2b(v.w);
    *(u16x4*)((unsigned short*)dst + i) = s;           // 8B vector store
}

// ---------------- GEMM 128x128 tile, ring-2 (r7-proven schedule) ----------------
// C[M,N] = epi( A[M,KR slice] @ W[N,KR slice]^T (+bias) (+R) ), A,W bf16.
// 256 threads = 4 waves (2M x 2N); per-wave C = 64x64 (acc 4x4 f4v).
// Round-12: r7 config restored everywhere. Session A/B ledger on this kernel:
//   r8 wide tile (3 WG/CU): REJECTED (-10%); r9 launch_bounds(256,5): REJECTED
//   (acc spill, VALUBusy 47->11%); r11 split-K atomics: REJECTED (FFN2 89->120us,
//   scattered 4B atomic RMW). Proven wins kept: conflict-free swizzle (r5:
//   conflicts 6.29M->0), supertile XCD map (r7: FETCH 239->51MB), coalesced
//   staged epilogue (r3: WRITE 161.6->65.5MB), 4 WG/CU (r7: best measured).
template<int EPI, bool HASRES, typename CT, int KL, int KR>
__global__ __launch_bounds__(256, 4)
void gemm128(const bf16* __restrict__ A, const bf16* __restrict__ W,
             const float* __restrict__ bias, const float* __restrict__ Rr,
             CT* __restrict__ C, int N)
{
    extern __shared__ __align__(16) unsigned short lds[];
    constexpr int NT   = KL / 32;
    constexpr int SLOT = 8192;

    // XCD supertile swizzle (gridDim.x == 64): XCD x owns bm strips {8x..8x+7}.
    const int o     = blockIdx.y * gridDim.x + blockIdx.x;
    const int local = o >> 3;
    const int bm  = (o & 7) * 8 + (local & 7);
    const int bn  = local >> 3;
    const long row0 = (long)bm * 128;
    const long col0 = (long)bn * 128;
    const long koff = (long)blockIdx.z * KL;

    const int tid  = threadIdx.x;
    const int lane = tid & 63;
    const int wave = tid >> 6;
    const int wm = wave >> 1;
    const int wn = wave & 1;
    const int fr = lane & 15;
    const int q4 = (lane >> 4) * 4;
    const int ksw = (((lane >> 4) ^ ((lane >> 1) & 3)) << 3);

    const int srow = tid >> 2;
    const int csrc = (tid & 3) ^ ((srow >> 1) & 3);
    const unsigned short* gA = (const unsigned short*)A + (row0 + srow) * (long)KR + koff + csrc * 8;
    const unsigned short* gB = (const unsigned short*)W + (col0 + srow) * (long)KR + koff + csrc * 8;
    const int woff = wave * 512;

    auto stage = [&](int t) {
        const long k0 = (long)t * 32;
        unsigned short* sl = lds + (t & 1) * SLOT + woff;
        gld16(gA + k0,                  sl);
        gld16(gA + 64 * (long)KR + k0,  sl + 2048);
        gld16(gB + k0,                  sl + 4096);
        gld16(gB + 64 * (long)KR + k0,  sl + 6144);
    };

    f4v acc[4][4];
#pragma unroll
    for (int i = 0; i < 4; ++i)
#pragma unroll
        for (int j = 0; j < 4; ++j) acc[i][j] = {0.f, 0.f, 0.f, 0.f};

    stage(0);
    __syncthreads();

#pragma unroll 2
    for (int t = 0; t < NT; ++t) {
        if (t + 1 < NT) stage(t + 1);

        const unsigned short* sA = lds + (t & 1) * SLOT;
        const unsigned short* sB = sA + 4096;

        bf8v afrag[4], bfrag[4];
#pragma unroll
        for (int x = 0; x < 4; ++x) {
            afrag[x] = *(const bf8v*)&sA[(wm * 64 + x * 16 + fr) * 32 + ksw];
            bfrag[x] = *(const bf8v*)&sB[(wn * 64 + x * 16 + fr) * 32 + ksw];
        }
#pragma unroll
        for (int mi = 0; mi < 4; ++mi)
#pragma unroll
            for (int ni = 0; ni < 4; ++ni)
                acc[mi][ni] = __builtin_amdgcn_mfma_f32_16x16x32_bf16(
                    afrag[mi], bfrag[ni], acc[mi][ni], 0, 0, 0);

        __syncthreads();
    }

    // coalesced LDS-staged epilogue (r3/r7-verified, 64-row chunks)
    constexpr int STR = 132;
    float* eb = (float*)lds;
    const int lcol  = (tid & 31) * 4;
    const long nbase = col0 + lcol;
    const float4 b4 = *(const float4*)&bias[nbase];
    const float bb[4] = {b4.x, b4.y, b4.z, b4.w};

#pragma unroll
    for (int h = 0; h < 2; ++h) {
        if (h) __syncthreads();
        if (wm == h) {
#pragma unroll
            for (int mi = 0; mi < 4; ++mi)
#pragma unroll
                for (int ni = 0; ni < 4; ++ni)
#pragma unroll
                    for (int r = 0; r < 4; ++r)
                        eb[(mi * 16 + q4 + r) * STR + wn * 64 + ni * 16 + fr] = acc[mi][ni][r];
        }
        __syncthreads();
#pragma unroll
        for (int i = 0; i < 8; ++i) {
            const int  rh = i * 8 + (tid >> 5);
            const long gr = row0 + h * 64 + rh;
            const f4v v = *(const f4v*)&eb[rh * STR + lcol];
            float ov[4];
#pragma unroll
            for (int c = 0; c < 4; ++c) ov[c] = v[c] + bb[c];
            if (HASRES) {
                const float4 r4 = *(const float4*)&Rr[gr * (long)N + nbase];
                const float ra[4] = {r4.x, r4.y, r4.z, r4.w};
#pragma unroll
                for (int c = 0; c < 4; ++c) ov[c] += ra[c];
            }
            if (EPI == 1) {
#pragma unroll
                for (int c = 0; c < 4; ++c) ov[c] = gelu_act(ov[c]);
            }
            if constexpr (sizeof(CT) == 2) {
                ushort4 s;
                bf16* sp = (bf16*)&s;
#pragma unroll
                for (int c = 0; c < 4; ++c) sp[c] = __float2bfloat16(ov[c]);
                *(ushort4*)&C[gr * (long)N + nbase] = s;
            } else {
                *(float4*)&C[gr * (long)N + nbase] = make_float4(ov[0], ov[1], ov[2], ov[3]);
            }
        }
    }
}

// ---------------- per-position head attention (the einsum quirk) ----------------
// r12: vectorized qkv loads (2x u16x8 = 32B/lane/matrix) and output stores
// (2x u16x8) - was scalar 2B loads/stores (Guideline-13 violation, ~2x cost).
__global__ __launch_bounds__(256)
void attn_kernel(const bf16* __restrict__ qkv, bf16* __restrict__ scr)
{
    __shared__ float sb[4][3392];   // per wave: q[16][65], k[16][65], v[16][65], a[16][17]
    const int tid = threadIdx.x;
    const int wave = tid >> 6, lane = tid & 63;
    const int m = blockIdx.x * 4 + wave;       // global position in [0, 8192)

    float* q = sb[wave];
    float* k = q + 1040;
    float* v = k + 1040;
    float* a = v + 1040;

    // lane covers head hh = lane>>2, cols [dd, dd+16) of q,k,v  (1024 = 64 lanes x 16)
    {
        const unsigned short* rp = (const unsigned short*)(qkv + (size_t)m * 3072) + lane * 16;
        const int hh = lane >> 2, dd = (lane & 3) * 16;
        const u16x8 a0 = *(const u16x8*)(rp);
        const u16x8 a1 = *(const u16x8*)(rp + 8);
        const u16x8 b0 = *(const u16x8*)(rp + 1024);
        const u16x8 b1 = *(const u16x8*)(rp + 1032);
        const u16x8 c0 = *(const u16x8*)(rp + 2048);
        const u16x8 c1 = *(const u16x8*)(rp + 2056);
        float* qdst = q + hh * 65 + dd;
        float* kdst = k + hh * 65 + dd;
        float* vdst = v + hh * 65 + dd;
#pragma unroll
        for (int j = 0; j < 8; ++j) {
            qdst[j] = b2f(a0[j]); qdst[8 + j] = b2f(a1[j]);
            kdst[j] = b2f(b0[j]); kdst[8 + j] = b2f(b1[j]);
            vdst[j] = b2f(c0[j]); vdst[8 + j] = b2f(c1[j]);
        }
    }
    __syncthreads();

    const int h1 = lane & 15, qd = lane >> 4;
    float e[4];
#pragma unroll
    for (int j = 0; j < 4; ++j) {
        const float* qr = q + h1 * 65;
        const float* kr = k + (qd * 4 + j) * 65;
        float s0 = 0.f;
        for (int d = 0; d < 64; ++d) s0 += qr[d] * kr[d];
        e[j] = s0 * 0.03125f;                  // 1/sqrt(1024)
    }
    float mx = fmaxf(fmaxf(e[0], e[1]), fmaxf(e[2], e[3]));
    mx = fmaxf(mx, __shfl_xor(mx, 16, 64));
    mx = fmaxf(mx, __shfl_xor(mx, 32, 64));
    float p[4], ps = 0.f;
#pragma unroll
    for (int j = 0; j < 4; ++j) { p[j] = expf(e[j] - mx); ps += p[j]; }
    ps += __shfl_xor(ps, 16, 64);
    ps += __shfl_xor(ps, 32, 64);
    const float inv = 1.f / ps;
#pragma unroll
    for (int j = 0; j < 4; ++j) a[h1 * 17 + qd * 4 + j] = p[j] * inv;
    __syncthreads();

    const int h = lane & 15, dg = lane >> 4;
    float arow[16];
#pragma unroll
    for (int l2 = 0; l2 < 16; ++l2) arow[l2] = a[h * 17 + l2];
    const int b = m >> 11, j = m & 2047;
    bf16* op = scr + (((size_t)b * 2048 + h * 128 + (j >> 4)) * 1024 + (j & 15) * 64);

    float ov[16];
#pragma unroll
    for (int t = 0; t < 16; ++t) {
        float o = 0.f;
#pragma unroll
        for (int l2 = 0; l2 < 16; ++l2) o += arow[l2] * v[l2 * 65 + dg * 16 + t];
        ov[t] = o;
    }
    u16x8 s0, s1;
#pragma unroll
    for (int jj = 0; jj < 8; ++jj) { s0[jj] = f2b(ov[jj]); s1[jj] = f2b(ov[8 + jj]); }
    *(u16x8*)((unsigned short*)op + dg * 16)     = s0;   // 16B store
    *(u16x8*)((unsigned short*)op + dg * 16 + 8) = s1;   // 16B store
}

// -------- row LayerNorm over E=1024, fp32 in, fp32 out (+optional bf16 copy) --------
__global__ __launch_bounds__(256)
void ln_kernel(const float* __restrict__ X, const float* __restrict__ G,
               const float* __restrict__ Bt, float* __restrict__ Y32,
               bf16* __restrict__ Yb)
{
    __shared__ float rs[4], rq[4];
    const int tid = threadIdx.x;
    const long row = blockIdx.x;
    const float* xp = X + row * 1024;
    float x[4];
#pragma unroll
    for (int i = 0; i < 4; ++i) x[i] = xp[tid + 256 * i];

    float s = x[0] + x[1] + x[2] + x[3];
#pragma unroll
    for (int off = 32; off; off >>= 1) s += __shfl_down(s, off, 64);
    if ((tid & 63) == 0) rs[tid >> 6] = s;
    __syncthreads();
    const float mean = (rs[0] + rs[1] + rs[2] + rs[3]) * (1.f / 1024.f);

    float qv = 0.f;
#pragma unroll
    for (int i = 0; i < 4; ++i) { float d = x[i] - mean; qv += d * d; }
#pragma unroll
    for (int off = 32; off; off >>= 1) qv += __shfl_down(qv, off, 64);
    if ((tid & 63) == 0) rq[tid >> 6] = qv;
    __syncthreads();
    const float var = (rq[0] + rq[1] + rq[2] + rq[3]) * (1.f / 1024.f);
    const float rstd = rsqrtf(var + 1e-5f);

#pragma unroll
    for (int i = 0; i < 4; ++i) {
        const int e = tid + 256 * i;
        const float yv = (x[i] - mean) * rstd * G[e] + Bt[e];
        Y32[row * 1024 + e] = yv;
        if (Yb) Yb[row * 1024 + e] = __float2bfloat16(yv);
    }
}

extern "C" void kernel_launch(void* const* d_in, const int* in_sizes, int n_in,
                              void* d_out, int out_size, void* d_ws, size_t ws_size,
                              hipStream_t stream)
{
    (void)in_sizes; (void)n_in; (void)out_size;
    const float* x    = (const float*)d_in[0];
    const float* Wqkv = (const float*)d_in[1];
    const float* bqkv = (const float*)d_in[2];
    const float* Wo   = (const float*)d_in[3];
    const float* bo   = (const float*)d_in[4];
    const float* g1   = (const float*)d_in[5];
    const float* b1   = (const float*)d_in[6];
    const float* W1   = (const float*)d_in[7];
    const float* bf1  = (const float*)d_in[8];
    const float* W2   = (const float*)d_in[9];
    const float* bf2  = (const float*)d_in[10];
    const float* g2   = (const float*)d_in[11];
    const float* b2   = (const float*)d_in[12];
    float* out = (float*)d_out;

    if (ws_size < 125829120ULL) return;

    // ws layout (bytes):
    //   R1 @0, 67,108,864: qkv bf16(50.3M) -> t fp32(33.5M) -> u bf16(67M)
    //   Wqkvb @67108864 (6.3M) | Wob @73400320 (2.1M) | W1b @75497472 (8.4M)
    //   W2b @83886080 (8.4M)   | xb/scr @92274688 (16.8M) | hb @109051904 (16.8M)
    char* ws = (char*)d_ws;
    bf16* qkv   = (bf16*)(ws + 0);
    float* t    = (float*)(ws + 0);
    bf16* u     = (bf16*)(ws + 0);
    bf16* Wqkvb = (bf16*)(ws + 67108864);
    bf16* Wob   = (bf16*)(ws + 73400320);
    bf16* W1b   = (bf16*)(ws + 75497472);
    bf16* W2b   = (bf16*)(ws + 83886080);
    bf16* xb    = (bf16*)(ws + 92274688);
    bf16* scr   = (bf16*)(ws + 92274688);   // reuses xb (dead after gemm1)
    bf16* hb    = (bf16*)(ws + 109051904);
    float* h    = out;                       // fp32 h lives in d_out until gemm6

    constexpr unsigned LDS_128 = 33792;      // ring 32K; 64-row epi stage 33,792 -> 4 WG/CU

    // 0) fused casts fp32 -> bf16 (one launch: x | Wqkv | Wo | W1 | W2)
    cast_all<<<20480, 256, 0, stream>>>(x, Wqkv, Wo, W1, W2, xb, Wqkvb, Wob, W1b, W2b);

    // 1) qkv = x @ Wqkv^T + bqkv            (bf16 out)   grid 64x24 = 1536 wg
    gemm128<0, false, bf16, 1024, 1024><<<dim3(64, 24), 256, LDS_128, stream>>>(xb, Wqkvb, bqkv, nullptr, qkv, 3072);
    // 2) per-position head attention + reshape scramble -> scr
    attn_kernel<<<2048, 256, 0, stream>>>(qkv, scr);
    // 3) t = scr @ Wo^T + bo + x            (fp32 out, fp32 residual)  grid 64x8 = 512 wg
    gemm128<0, true, float, 1024, 1024><<<dim3(64, 8), 256, LDS_128, stream>>>(scr, Wob, bo, x, t, 1024);
    // 4) h = LN1(t)  -> fp32 h (d_out) + bf16 hb
    ln_kernel<<<8192, 256, 0, stream>>>(t, g1, b1, h, hb);
    // 5) u = gelu(hb @ W1^T + bf1)          (bf16 out)   grid 64x32 = 2048 wg
    gemm128<1, false, bf16, 1024, 1024><<<dim3(64, 32), 256, LDS_128, stream>>>(hb, W1b, bf1, nullptr, u, 4096);
    // 6) s2 = u @ W2^T + bf2 + h            (fp32 out aliasing R=h elementwise)  grid 64x8 = 512 wg
    gemm128<0, true, float, 4096, 4096><<<dim3(64, 8), 256, LDS_128, stream>>>(u, W2b, bf2, h, out, 1024);
    // 7) out = LN2(s2) in-place, fp32 only
    ln_kernel<<<8192, 256, 0, stream>>>(out, g2, b2, out, nullptr);
}